// Round 1
// baseline (449.196 us; speedup 1.0000x reference)
//
#include <hip/hip_runtime.h>
#include <hip/hip_bf16.h>
#include <stdint.h>

// GCN: out = D^-1/2 A D^-1/2 X W + b
// B=4, N=4096, F_IN=F_OUT=128, all fp32 I/O.
// v3: fuse bf16(adj) conversion into the degree pass (adjh = 128 MiB fits the
// 256 MiB L3; fp32 adj at 256 MiB exactly cannot stay resident). GEMM reads
// bf16 A directly: half the A bytes, L3-hit, no per-iter cvt/repack. W is
// pre-transposed to bf16 (wt[o][f]) so the epilogue B-frag is one 16 B load.
// Fallback to the v2 fp32-adj path if ws_size is too small for adjh.

#define NROW 4096
#define FDIM 128
#define NBATCH 4

typedef __bf16 bf16x8 __attribute__((ext_vector_type(8)));
typedef float f32x4 __attribute__((ext_vector_type(4)));

// ---------------- kernel 1 (new): degree + d^{-1/2} + bf16 copy of adj ------
// one WAVE per row: 64 lanes x 16 float4 = 16 KB row. adj values are already
// in registers -> bf16 convert+store is free VALU under a BW-bound kernel.
__global__ __launch_bounds__(256) void k_degree_cvt(const float* __restrict__ adj,
                                                    float* __restrict__ dinv,
                                                    __hip_bfloat16* __restrict__ adjh) {
  const int row = blockIdx.x * 4 + (threadIdx.x >> 6);  // b*NROW+n
  const int lane = threadIdx.x & 63;
  const float4* arow = (const float4*)(adj + (size_t)row * NROW);
  ushort4* hrow = (ushort4*)(adjh + (size_t)row * NROW);
  float s = 0.f;
#pragma unroll
  for (int i = 0; i < 16; ++i) {
    float4 v = arow[lane + i * 64];
    s += (v.x + v.y) + (v.z + v.w);
    union { __hip_bfloat16 h[4]; ushort4 u; } t;
    t.h[0] = __float2bfloat16(v.x);
    t.h[1] = __float2bfloat16(v.y);
    t.h[2] = __float2bfloat16(v.z);
    t.h[3] = __float2bfloat16(v.w);
    hrow[lane + i * 64] = t.u;
  }
#pragma unroll
  for (int off = 32; off > 0; off >>= 1) s += __shfl_down(s, off, 64);
  if (lane == 0) dinv[row] = 1.0f / sqrtf(s + 1e-6f);
}

// ---------------- kernel 1 (fallback): degree only --------------------------
__global__ __launch_bounds__(256) void k_degree(const float* __restrict__ adj,
                                                float* __restrict__ dinv) {
  const int row = blockIdx.x * 4 + (threadIdx.x >> 6);
  const int lane = threadIdx.x & 63;
  const float4* arow = (const float4*)(adj + (size_t)row * NROW);
  float s = 0.f;
#pragma unroll
  for (int i = 0; i < 16; ++i) {
    float4 v = arow[lane + i * 64];
    s += (v.x + v.y) + (v.z + v.w);
  }
#pragma unroll
  for (int off = 32; off > 0; off >>= 1) s += __shfl_down(s, off, 64);
  if (lane == 0) dinv[row] = 1.0f / sqrtf(s + 1e-6f);
}

// ---------------- kernel 2: Xst[b][f][m] = bf16(dinv[b,m] * x[b][m][f]) ----
// blocks 0..511: xst transpose+scale. block 512 (new path only): wt[o][f] =
// bf16(W[f][o]) -- 32 KB, makes epilogue B-frag a single 16 B load.
__global__ __launch_bounds__(256) void k_xst(const float* __restrict__ x,
                                             const float* __restrict__ dinv,
                                             __hip_bfloat16* __restrict__ xst,
                                             const float* __restrict__ w,
                                             __hip_bfloat16* __restrict__ wt) {
  const int bid = blockIdx.x;
  const int tid = threadIdx.x;

  if (bid == 512) {  // W transpose -> bf16
    const int o = tid >> 1;
    const int f0 = (tid & 1) * 64;
    union { __hip_bfloat16 h[64]; uint4 v[8]; } t;
#pragma unroll
    for (int j = 0; j < 64; ++j)
      t.h[j] = __float2bfloat16(w[(size_t)(f0 + j) * FDIM + o]);
    uint4* dst = (uint4*)(wt + (size_t)o * FDIM + f0);
#pragma unroll
    for (int j = 0; j < 8; ++j) dst[j] = t.v[j];
    return;
  }

  const int b = bid >> 7;            // 0..3
  const int m0 = (bid & 127) * 32;   // 0..4064
  __shared__ float tile[32 * 132];
  {
    const int ml = tid >> 3;          // 0..31
    const int fl = (tid & 7) * 16;    // 0..112
    const float dv = dinv[b * NROW + m0 + ml];
    const float* gx = x + ((size_t)b * NROW + m0 + ml) * FDIM + fl;
    float* dst = &tile[ml * 132 + fl];
#pragma unroll
    for (int j = 0; j < 16; j += 4) {
      float4 v = *(const float4*)(gx + j);
      v.x *= dv; v.y *= dv; v.z *= dv; v.w *= dv;
      *(float4*)(dst + j) = v;
    }
  }
  __syncthreads();
  {
    const int f = tid >> 1;           // 0..127
    const int mc = (tid & 1) * 16;    // 0 or 16
    union { __hip_bfloat16 h[16]; uint4 v[2]; } tmp;
#pragma unroll
    for (int j = 0; j < 16; ++j)
      tmp.h[j] = __float2bfloat16(tile[(mc + j) * 132 + f]);
    __hip_bfloat16* dst = xst + ((size_t)b * FDIM + f) * NROW + m0 + mc;
    *(uint4*)(dst) = tmp.v[0];
    *(uint4*)(dst + 8) = tmp.v[1];
  }
}

// ---------------- kernel 3 (new): GEMM on bf16 adjh + fused epilogue --------
#define MT 32
#define KC 64
#define AS_ST 72    // 64+8 bf16
#define BS_ST 72
#define ZS_ST 136   // 128+8

__global__ __launch_bounds__(256, 2)
void k_gemm_h(const __hip_bfloat16* __restrict__ adjh, const __hip_bfloat16* __restrict__ xst,
              const float* __restrict__ dinv, const __hip_bfloat16* __restrict__ wt,
              const float* __restrict__ bias, float* __restrict__ out) {
  __shared__ union {
    struct { __hip_bfloat16 As[2][MT * AS_ST]; __hip_bfloat16 Bs[2][FDIM * BS_ST]; } lp;
    __hip_bfloat16 Zs[MT * ZS_ST];
  } sm;
  __shared__ float dinv_s[MT];

  const int bid = blockIdx.x;            // 0..511
  const int xcd = bid & 7;
  const int b = xcd >> 1;                // same batch stays on an XCD pair
  const int mtile = (bid >> 3) * 2 + (xcd & 1);
  const int row0 = mtile * MT;

  const int tid = threadIdx.x;
  const int lane = tid & 63;
  const int wid = tid >> 6;
  const int l16 = lane & 15;
  const int quad = lane >> 4;

  if (tid < MT) dinv_s[tid] = dinv[b * NROW + row0 + tid];

  const __hip_bfloat16* adjh_b = adjh + ((size_t)b * NROW + row0) * NROW;
  const __hip_bfloat16* xst_b = xst + (size_t)b * FDIM * NROW;

  f32x4 zero4;
  zero4.x = 0.f; zero4.y = 0.f; zero4.z = 0.f; zero4.w = 0.f;
  f32x4 acc[2][2];
#pragma unroll
  for (int rt = 0; rt < 2; ++rt)
#pragma unroll
    for (int ct = 0; ct < 2; ++ct) acc[rt][ct] = zero4;

  // staging indices: A bf16 row chunk = 1 uint4 per thread per iter
  const int ar = tid >> 3;          // A: row 0..31
  const int ac = (tid & 7) * 8;     // A: k-offset, 8 bf16 = 16 B
  const int bfr = tid >> 1;         // B: f-row 0..127
  const int bcc = (tid & 1) * 32;   // B: k-offset 0 or 32
  const __hip_bfloat16* ga = adjh_b + (size_t)ar * NROW + ac;
  const __hip_bfloat16* gb = xst_b + (size_t)bfr * NROW + bcc;

  // prologue: prefetch tile 0 into registers
  uint4 pa = *(const uint4*)(ga);
  uint4 pb0 = ((const uint4*)gb)[0];
  uint4 pb1 = ((const uint4*)gb)[1];
  uint4 pb2 = ((const uint4*)gb)[2];
  uint4 pb3 = ((const uint4*)gb)[3];

  int p = 0;
  for (int k0 = 0; k0 < NROW; k0 += KC) {
    {  // drain prefetch regs -> LDS buf[p] (no cvt needed anymore)
      *(uint4*)&sm.lp.As[p][ar * AS_ST + ac] = pa;
      __hip_bfloat16* q = &sm.lp.Bs[p][bfr * BS_ST + bcc];
      *(uint4*)(q) = pb0;
      *(uint4*)(q + 8) = pb1;
      *(uint4*)(q + 16) = pb2;
      *(uint4*)(q + 24) = pb3;
    }
    if (k0 + KC < NROW) {
      pa = *(const uint4*)(ga + k0 + KC);
      const __hip_bfloat16* gbn = gb + k0 + KC;
      pb0 = ((const uint4*)gbn)[0];
      pb1 = ((const uint4*)gbn)[1];
      pb2 = ((const uint4*)gbn)[2];
      pb3 = ((const uint4*)gbn)[3];
    }
    __syncthreads();
#pragma unroll
    for (int kk = 0; kk < 2; ++kk) {
      bf16x8 af[2], bfv[2];
#pragma unroll
      for (int rt = 0; rt < 2; ++rt)
        af[rt] = *(const bf16x8*)&sm.lp.As[p][(rt * 16 + l16) * AS_ST + kk * 32 + quad * 8];
#pragma unroll
      for (int ct = 0; ct < 2; ++ct)
        bfv[ct] = *(const bf16x8*)&sm.lp.Bs[p][(wid * 32 + ct * 16 + l16) * BS_ST + kk * 32 + quad * 8];
#pragma unroll
      for (int rt = 0; rt < 2; ++rt)
#pragma unroll
        for (int ct = 0; ct < 2; ++ct)
          acc[rt][ct] = __builtin_amdgcn_mfma_f32_16x16x32_bf16(af[rt], bfv[ct], acc[rt][ct], 0, 0, 0);
    }
    p ^= 1;
  }
  __syncthreads();

  // epilogue: Z (scaled by dinv[n]) -> LDS bf16. C/D: col=lane&15, row=quad*4+reg.
#pragma unroll
  for (int rt = 0; rt < 2; ++rt)
#pragma unroll
    for (int ct = 0; ct < 2; ++ct)
#pragma unroll
      for (int i = 0; i < 4; ++i) {
        int r = rt * 16 + quad * 4 + i;
        int c = wid * 32 + ct * 16 + l16;
        sm.Zs[r * ZS_ST + c] = __float2bfloat16(acc[rt][ct][i] * dinv_s[r]);
      }
  __syncthreads();

  // second GEMM: Z @ W via pre-transposed bf16 wt[o][f] (32 KB, L2-resident):
  // B-frag element j = W[f=kk*32+quad*8+j][o] = wt[o*128 + kk*32+quad*8+j].
  f32x4 acc2[2][2];
#pragma unroll
  for (int rt = 0; rt < 2; ++rt)
#pragma unroll
    for (int ct = 0; ct < 2; ++ct) acc2[rt][ct] = zero4;
#pragma unroll
  for (int kk = 0; kk < 4; ++kk) {
    bf16x8 za[2], wb[2];
#pragma unroll
    for (int rt = 0; rt < 2; ++rt)
      za[rt] = *(const bf16x8*)&sm.Zs[(rt * 16 + l16) * ZS_ST + kk * 32 + quad * 8];
#pragma unroll
    for (int ct = 0; ct < 2; ++ct) {
      const int o = wid * 32 + ct * 16 + l16;
      wb[ct] = *(const bf16x8*)&wt[(size_t)o * FDIM + kk * 32 + quad * 8];
    }
#pragma unroll
    for (int rt = 0; rt < 2; ++rt)
#pragma unroll
      for (int ct = 0; ct < 2; ++ct)
        acc2[rt][ct] = __builtin_amdgcn_mfma_f32_16x16x32_bf16(za[rt], wb[ct], acc2[rt][ct], 0, 0, 0);
  }

  float bv[2];
  bv[0] = bias[wid * 32 + l16];
  bv[1] = bias[wid * 32 + 16 + l16];
  float* ob = out + ((size_t)b * NROW + row0) * FDIM;
#pragma unroll
  for (int rt = 0; rt < 2; ++rt)
#pragma unroll
    for (int ct = 0; ct < 2; ++ct)
#pragma unroll
      for (int i = 0; i < 4; ++i) {
        int r = rt * 16 + quad * 4 + i;
        int o = wid * 32 + ct * 16 + l16;
        ob[(size_t)r * FDIM + o] = acc2[rt][ct][i] + bv[ct];
      }
}

// ---------------- kernel 3 (fallback): v2 GEMM on fp32 adj ------------------
__global__ __launch_bounds__(256, 2)
void k_gemm_f32(const float* __restrict__ adj, const __hip_bfloat16* __restrict__ xst,
                const float* __restrict__ dinv, const float* __restrict__ w,
                const float* __restrict__ bias, float* __restrict__ out) {
  __shared__ union {
    struct { __hip_bfloat16 As[2][MT * AS_ST]; __hip_bfloat16 Bs[2][FDIM * BS_ST]; } lp;
    __hip_bfloat16 Zs[MT * ZS_ST];
  } sm;
  __shared__ float dinv_s[MT];

  const int bid = blockIdx.x;
  const int xcd = bid & 7;
  const int b = xcd >> 1;
  const int mtile = (bid >> 3) * 2 + (xcd & 1);
  const int row0 = mtile * MT;

  const int tid = threadIdx.x;
  const int lane = tid & 63;
  const int wid = tid >> 6;
  const int l16 = lane & 15;
  const int quad = lane >> 4;

  if (tid < MT) dinv_s[tid] = dinv[b * NROW + row0 + tid];

  const float* adj_b = adj + ((size_t)b * NROW + row0) * NROW;
  const __hip_bfloat16* xst_b = xst + (size_t)b * FDIM * NROW;

  f32x4 zero4;
  zero4.x = 0.f; zero4.y = 0.f; zero4.z = 0.f; zero4.w = 0.f;
  f32x4 acc[2][2];
#pragma unroll
  for (int rt = 0; rt < 2; ++rt)
#pragma unroll
    for (int ct = 0; ct < 2; ++ct) acc[rt][ct] = zero4;

  const int ar = tid >> 3;
  const int ac = (tid & 7) * 8;
  const int bfr = tid >> 1;
  const int bcc = (tid & 1) * 32;
  const float* ga = adj_b + (size_t)ar * NROW + ac;
  const __hip_bfloat16* gb = xst_b + (size_t)bfr * NROW + bcc;

  float4 pa0 = *(const float4*)(ga);
  float4 pa1 = *(const float4*)(ga + 4);
  uint4 pb0 = ((const uint4*)gb)[0];
  uint4 pb1 = ((const uint4*)gb)[1];
  uint4 pb2 = ((const uint4*)gb)[2];
  uint4 pb3 = ((const uint4*)gb)[3];

  int p = 0;
  for (int k0 = 0; k0 < NROW; k0 += KC) {
    {
      union { __hip_bfloat16 h[8]; uint4 u; } t;
      t.h[0] = __float2bfloat16(pa0.x); t.h[1] = __float2bfloat16(pa0.y);
      t.h[2] = __float2bfloat16(pa0.z); t.h[3] = __float2bfloat16(pa0.w);
      t.h[4] = __float2bfloat16(pa1.x); t.h[5] = __float2bfloat16(pa1.y);
      t.h[6] = __float2bfloat16(pa1.z); t.h[7] = __float2bfloat16(pa1.w);
      *(uint4*)&sm.lp.As[p][ar * AS_ST + ac] = t.u;
      __hip_bfloat16* q = &sm.lp.Bs[p][bfr * BS_ST + bcc];
      *(uint4*)(q) = pb0;
      *(uint4*)(q + 8) = pb1;
      *(uint4*)(q + 16) = pb2;
      *(uint4*)(q + 24) = pb3;
    }
    if (k0 + KC < NROW) {
      const float* gan = ga + k0 + KC;
      pa0 = *(const float4*)(gan);
      pa1 = *(const float4*)(gan + 4);
      const __hip_bfloat16* gbn = gb + k0 + KC;
      pb0 = ((const uint4*)gbn)[0];
      pb1 = ((const uint4*)gbn)[1];
      pb2 = ((const uint4*)gbn)[2];
      pb3 = ((const uint4*)gbn)[3];
    }
    __syncthreads();
#pragma unroll
    for (int kk = 0; kk < 2; ++kk) {
      bf16x8 af[2], bfv[2];
#pragma unroll
      for (int rt = 0; rt < 2; ++rt)
        af[rt] = *(const bf16x8*)&sm.lp.As[p][(rt * 16 + l16) * AS_ST + kk * 32 + quad * 8];
#pragma unroll
      for (int ct = 0; ct < 2; ++ct)
        bfv[ct] = *(const bf16x8*)&sm.lp.Bs[p][(wid * 32 + ct * 16 + l16) * BS_ST + kk * 32 + quad * 8];
#pragma unroll
      for (int rt = 0; rt < 2; ++rt)
#pragma unroll
        for (int ct = 0; ct < 2; ++ct)
          acc[rt][ct] = __builtin_amdgcn_mfma_f32_16x16x32_bf16(af[rt], bfv[ct], acc[rt][ct], 0, 0, 0);
    }
    p ^= 1;
  }
  __syncthreads();

#pragma unroll
  for (int rt = 0; rt < 2; ++rt)
#pragma unroll
    for (int ct = 0; ct < 2; ++ct)
#pragma unroll
      for (int i = 0; i < 4; ++i) {
        int r = rt * 16 + quad * 4 + i;
        int c = wid * 32 + ct * 16 + l16;
        sm.Zs[r * ZS_ST + c] = __float2bfloat16(acc[rt][ct][i] * dinv_s[r]);
      }
  __syncthreads();

  f32x4 acc2[2][2];
#pragma unroll
  for (int rt = 0; rt < 2; ++rt)
#pragma unroll
    for (int ct = 0; ct < 2; ++ct) acc2[rt][ct] = zero4;
#pragma unroll
  for (int kk = 0; kk < 4; ++kk) {
    bf16x8 za[2], wb[2];
#pragma unroll
    for (int rt = 0; rt < 2; ++rt)
      za[rt] = *(const bf16x8*)&sm.Zs[(rt * 16 + l16) * ZS_ST + kk * 32 + quad * 8];
#pragma unroll
    for (int ct = 0; ct < 2; ++ct) {
      const int o = wid * 32 + ct * 16 + l16;
      const float* gw = w + (kk * 32 + quad * 8) * FDIM + o;
      union { __hip_bfloat16 h[8]; bf16x8 v; } tw;
#pragma unroll
      for (int j = 0; j < 8; ++j)
        tw.h[j] = __float2bfloat16(gw[j * FDIM]);
      wb[ct] = tw.v;
    }
#pragma unroll
    for (int rt = 0; rt < 2; ++rt)
#pragma unroll
      for (int ct = 0; ct < 2; ++ct)
        acc2[rt][ct] = __builtin_amdgcn_mfma_f32_16x16x32_bf16(za[rt], wb[ct], acc2[rt][ct], 0, 0, 0);
  }

  float bv[2];
  bv[0] = bias[wid * 32 + l16];
  bv[1] = bias[wid * 32 + 16 + l16];
  float* ob = out + ((size_t)b * NROW + row0) * FDIM;
#pragma unroll
  for (int rt = 0; rt < 2; ++rt)
#pragma unroll
    for (int ct = 0; ct < 2; ++ct)
#pragma unroll
      for (int i = 0; i < 4; ++i) {
        int r = rt * 16 + quad * 4 + i;
        int o = wid * 32 + ct * 16 + l16;
        ob[(size_t)r * FDIM + o] = acc2[rt][ct][i] + bv[ct];
      }
}

extern "C" void kernel_launch(void* const* d_in, const int* in_sizes, int n_in,
                              void* d_out, int out_size, void* d_ws, size_t ws_size,
                              hipStream_t stream) {
  const float* x    = (const float*)d_in[0];   // [4,4096,128]
  const float* adj  = (const float*)d_in[1];   // [4,4096,4096]
  const float* w    = (const float*)d_in[2];   // [128,128]
  const float* bias = (const float*)d_in[3];   // [128]
  float* out = (float*)d_out;                  // [4,4096,128]

  const size_t OFF_DINV = 0;
  const size_t OFF_XST  = 65536;                           // 64 KB dinv
  const size_t OFF_WT   = OFF_XST + 4194304;               // 4 MiB xst
  const size_t OFF_ADJH = OFF_WT + 32768;                  // 32 KB wt
  const size_t NEED = OFF_ADJH + (size_t)NBATCH * NROW * NROW * 2;  // +128 MiB

  float* dinv = (float*)((char*)d_ws + OFF_DINV);
  __hip_bfloat16* xst  = (__hip_bfloat16*)((char*)d_ws + OFF_XST);
  __hip_bfloat16* wt   = (__hip_bfloat16*)((char*)d_ws + OFF_WT);
  __hip_bfloat16* adjh = (__hip_bfloat16*)((char*)d_ws + OFF_ADJH);

  if (ws_size >= NEED) {
    k_degree_cvt<<<NBATCH * NROW / 4, 256, 0, stream>>>(adj, dinv, adjh);
    k_xst<<<513, 256, 0, stream>>>(x, dinv, xst, w, wt);
    k_gemm_h<<<512, 256, 0, stream>>>(adjh, xst, dinv, wt, bias, out);
  } else {
    k_degree<<<NBATCH * NROW / 4, 256, 0, stream>>>(adj, dinv);
    k_xst<<<512, 256, 0, stream>>>(x, dinv, xst, w, (__hip_bfloat16*)0);
    k_gemm_f32<<<512, 256, 0, stream>>>(adj, xst, dinv, w, bias, out);
  }
}

// Round 2
// 429.179 us; speedup vs baseline: 1.0466x; 1.0466x over previous
//
#include <hip/hip_runtime.h>
#include <hip/hip_bf16.h>
#include <stdint.h>

// GCN: out = D^-1/2 A D^-1/2 X W + b
// B=4, N=4096, F_IN=F_OUT=128, all fp32 I/O.
// v4: revert v3's adjh write (cost +128MiB HBM write, zero GEMM gain -> GEMM
// is latency-bound, not A-byte-bound). GEMM now uses a 2-tile-deep register
// prefetch (two named reg sets, explicit 2x-unrolled K loop -> static reg
// indexing) so the load->use distance spans ~2 full iterations and the
// per-iter vmcnt drain stall disappears. adj re-read in GEMM hits L3 (pass 1
// just streamed exactly L3-capacity through it). Keep bf16 wt[o][f] for the
// epilogue B-fragment (single 16 B load).

#define NROW 4096
#define FDIM 128
#define NBATCH 4

typedef __bf16 bf16x8 __attribute__((ext_vector_type(8)));
typedef float f32x4 __attribute__((ext_vector_type(4)));

// ---------------- kernel 1: degree + d^{-1/2} ----------------
// one WAVE per row: 64 lanes x 16 float4 = 16 KB row, no LDS, no barrier.
__global__ __launch_bounds__(256) void k_degree(const float* __restrict__ adj,
                                                float* __restrict__ dinv) {
  const int row = blockIdx.x * 4 + (threadIdx.x >> 6);  // b*NROW+n
  const int lane = threadIdx.x & 63;
  const float4* arow = (const float4*)(adj + (size_t)row * NROW);
  float s = 0.f;
#pragma unroll
  for (int i = 0; i < 16; ++i) {
    float4 v = arow[lane + i * 64];
    s += (v.x + v.y) + (v.z + v.w);
  }
#pragma unroll
  for (int off = 32; off > 0; off >>= 1) s += __shfl_down(s, off, 64);
  if (lane == 0) dinv[row] = 1.0f / sqrtf(s + 1e-6f);
}

// ---------------- kernel 2: Xst[b][f][m] = bf16(dinv[b,m] * x[b][m][f]) ----
// blocks 0..511: xst transpose+scale. block 512: wt[o][f] = bf16(W[f][o]).
__global__ __launch_bounds__(256) void k_xst(const float* __restrict__ x,
                                             const float* __restrict__ dinv,
                                             __hip_bfloat16* __restrict__ xst,
                                             const float* __restrict__ w,
                                             __hip_bfloat16* __restrict__ wt) {
  const int bid = blockIdx.x;
  const int tid = threadIdx.x;

  if (bid == 512) {  // W transpose -> bf16 (32 KB, one block)
    const int o = tid >> 1;
    const int f0 = (tid & 1) * 64;
    union { __hip_bfloat16 h[64]; uint4 v[8]; } t;
#pragma unroll
    for (int j = 0; j < 64; ++j)
      t.h[j] = __float2bfloat16(w[(size_t)(f0 + j) * FDIM + o]);
    uint4* dst = (uint4*)(wt + (size_t)o * FDIM + f0);
#pragma unroll
    for (int j = 0; j < 8; ++j) dst[j] = t.v[j];
    return;
  }

  const int b = bid >> 7;            // 0..3
  const int m0 = (bid & 127) * 32;   // 0..4064
  __shared__ float tile[32 * 132];
  {
    const int ml = tid >> 3;          // 0..31
    const int fl = (tid & 7) * 16;    // 0..112
    const float dv = dinv[b * NROW + m0 + ml];
    const float* gx = x + ((size_t)b * NROW + m0 + ml) * FDIM + fl;
    float* dst = &tile[ml * 132 + fl];
#pragma unroll
    for (int j = 0; j < 16; j += 4) {
      float4 v = *(const float4*)(gx + j);
      v.x *= dv; v.y *= dv; v.z *= dv; v.w *= dv;
      *(float4*)(dst + j) = v;
    }
  }
  __syncthreads();
  {
    const int f = tid >> 1;           // 0..127
    const int mc = (tid & 1) * 16;    // 0 or 16
    union { __hip_bfloat16 h[16]; uint4 v[2]; } tmp;
#pragma unroll
    for (int j = 0; j < 16; ++j)
      tmp.h[j] = __float2bfloat16(tile[(mc + j) * 132 + f]);
    __hip_bfloat16* dst = xst + ((size_t)b * FDIM + f) * NROW + m0 + mc;
    *(uint4*)(dst) = tmp.v[0];
    *(uint4*)(dst + 8) = tmp.v[1];
  }
}

// ---------------- kernel 3: main GEMM + fused epilogue ----------------
// 32 rows x 128 cols of Z per block; Kc=64; 4 waves, each 32x32 (2x2 of
// 16x16x32 bf16 MFMA). 2-deep register prefetch + LDS dbuf: loads for tile
// k+2 are issued at tile k, so ~2 full iterations cover HBM/L3 latency.
#define MT 32
#define KC 64
#define AS_ST 72    // 64+8 bf16
#define BS_ST 72
#define ZS_ST 136   // 128+8

__global__ __launch_bounds__(256, 2)
void k_gemm(const float* __restrict__ adj, const __hip_bfloat16* __restrict__ xst,
            const float* __restrict__ dinv, const __hip_bfloat16* __restrict__ wt,
            const float* __restrict__ bias, float* __restrict__ out) {
  __shared__ union {
    struct { __hip_bfloat16 As[2][MT * AS_ST]; __hip_bfloat16 Bs[2][FDIM * BS_ST]; } lp; // 46080 B
    __hip_bfloat16 Zs[MT * ZS_ST];                                                       // 8704 B
  } sm;
  __shared__ float dinv_s[MT];

  // XCD swizzle: same batch stays on an XCD pair -> xst slice L2-resident.
  const int bid = blockIdx.x;            // 0..511
  const int xcd = bid & 7;
  const int b = xcd >> 1;                // 0..3
  const int mtile = (bid >> 3) * 2 + (xcd & 1);  // 0..127
  const int row0 = mtile * MT;

  const int tid = threadIdx.x;
  const int lane = tid & 63;
  const int wid = tid >> 6;   // 0..3
  const int l16 = lane & 15;
  const int quad = lane >> 4; // 0..3

  if (tid < MT) dinv_s[tid] = dinv[b * NROW + row0 + tid];

  const float* adj_b = adj + ((size_t)b * NROW + row0) * NROW;
  const __hip_bfloat16* xst_b = xst + (size_t)b * FDIM * NROW;

  f32x4 zero4;
  zero4.x = 0.f; zero4.y = 0.f; zero4.z = 0.f; zero4.w = 0.f;
  f32x4 acc[2][2];
#pragma unroll
  for (int rt = 0; rt < 2; ++rt)
#pragma unroll
    for (int ct = 0; ct < 2; ++ct) acc[rt][ct] = zero4;

  // staging indices
  const int ar = tid >> 3;          // A: row 0..31
  const int ac = (tid & 7) * 8;     // A: k-offset 0..56 (8 fp32 each)
  const int bfr = tid >> 1;         // B: f-row 0..127
  const int bcc = (tid & 1) * 32;   // B: k-offset 0 or 32 (32 bf16 each)
  const float* ga = adj_b + (size_t)ar * NROW + ac;
  const __hip_bfloat16* gb = xst_b + (size_t)bfr * NROW + bcc;

  // prologue: 2-deep prefetch -- set A holds tile 0, set B holds tile KC.
  float4 paA0 = *(const float4*)(ga);
  float4 paA1 = *(const float4*)(ga + 4);
  uint4 pbA0 = ((const uint4*)(gb))[0];
  uint4 pbA1 = ((const uint4*)(gb))[1];
  uint4 pbA2 = ((const uint4*)(gb))[2];
  uint4 pbA3 = ((const uint4*)(gb))[3];
  float4 paB0 = *(const float4*)(ga + KC);
  float4 paB1 = *(const float4*)(ga + KC + 4);
  uint4 pbB0 = ((const uint4*)(gb + KC))[0];
  uint4 pbB1 = ((const uint4*)(gb + KC))[1];
  uint4 pbB2 = ((const uint4*)(gb + KC))[2];
  uint4 pbB3 = ((const uint4*)(gb + KC))[3];

  for (int k0 = 0; k0 < NROW; k0 += 2 * KC) {
    // ======== even half: tile k0, LDS buf 0, reg set A ========
    {
      union { __hip_bfloat16 h[8]; uint4 u; } t;
      t.h[0] = __float2bfloat16(paA0.x); t.h[1] = __float2bfloat16(paA0.y);
      t.h[2] = __float2bfloat16(paA0.z); t.h[3] = __float2bfloat16(paA0.w);
      t.h[4] = __float2bfloat16(paA1.x); t.h[5] = __float2bfloat16(paA1.y);
      t.h[6] = __float2bfloat16(paA1.z); t.h[7] = __float2bfloat16(paA1.w);
      *(uint4*)&sm.lp.As[0][ar * AS_ST + ac] = t.u;
      __hip_bfloat16* q = &sm.lp.Bs[0][bfr * BS_ST + bcc];
      *(uint4*)(q) = pbA0;
      *(uint4*)(q + 8) = pbA1;
      *(uint4*)(q + 16) = pbA2;
      *(uint4*)(q + 24) = pbA3;
    }
    if (k0 + 2 * KC < NROW) {  // reload set A with tile k0+2*KC
      const float* gan = ga + k0 + 2 * KC;
      paA0 = *(const float4*)(gan);
      paA1 = *(const float4*)(gan + 4);
      const __hip_bfloat16* gbn = gb + k0 + 2 * KC;
      pbA0 = ((const uint4*)gbn)[0];
      pbA1 = ((const uint4*)gbn)[1];
      pbA2 = ((const uint4*)gbn)[2];
      pbA3 = ((const uint4*)gbn)[3];
    }
    __syncthreads();
#pragma unroll
    for (int kk = 0; kk < 2; ++kk) {
      bf16x8 af[2], bfv[2];
#pragma unroll
      for (int rt = 0; rt < 2; ++rt)
        af[rt] = *(const bf16x8*)&sm.lp.As[0][(rt * 16 + l16) * AS_ST + kk * 32 + quad * 8];
#pragma unroll
      for (int ct = 0; ct < 2; ++ct)
        bfv[ct] = *(const bf16x8*)&sm.lp.Bs[0][(wid * 32 + ct * 16 + l16) * BS_ST + kk * 32 + quad * 8];
#pragma unroll
      for (int rt = 0; rt < 2; ++rt)
#pragma unroll
        for (int ct = 0; ct < 2; ++ct)
          acc[rt][ct] = __builtin_amdgcn_mfma_f32_16x16x32_bf16(af[rt], bfv[ct], acc[rt][ct], 0, 0, 0);
    }

    // ======== odd half: tile k0+KC, LDS buf 1, reg set B ========
    {
      union { __hip_bfloat16 h[8]; uint4 u; } t;
      t.h[0] = __float2bfloat16(paB0.x); t.h[1] = __float2bfloat16(paB0.y);
      t.h[2] = __float2bfloat16(paB0.z); t.h[3] = __float2bfloat16(paB0.w);
      t.h[4] = __float2bfloat16(paB1.x); t.h[5] = __float2bfloat16(paB1.y);
      t.h[6] = __float2bfloat16(paB1.z); t.h[7] = __float2bfloat16(paB1.w);
      *(uint4*)&sm.lp.As[1][ar * AS_ST + ac] = t.u;
      __hip_bfloat16* q = &sm.lp.Bs[1][bfr * BS_ST + bcc];
      *(uint4*)(q) = pbB0;
      *(uint4*)(q + 8) = pbB1;
      *(uint4*)(q + 16) = pbB2;
      *(uint4*)(q + 24) = pbB3;
    }
    if (k0 + 3 * KC < NROW) {  // reload set B with tile k0+3*KC
      const float* gan = ga + k0 + 3 * KC;
      paB0 = *(const float4*)(gan);
      paB1 = *(const float4*)(gan + 4);
      const __hip_bfloat16* gbn = gb + k0 + 3 * KC;
      pbB0 = ((const uint4*)gbn)[0];
      pbB1 = ((const uint4*)gbn)[1];
      pbB2 = ((const uint4*)gbn)[2];
      pbB3 = ((const uint4*)gbn)[3];
    }
    __syncthreads();
#pragma unroll
    for (int kk = 0; kk < 2; ++kk) {
      bf16x8 af[2], bfv[2];
#pragma unroll
      for (int rt = 0; rt < 2; ++rt)
        af[rt] = *(const bf16x8*)&sm.lp.As[1][(rt * 16 + l16) * AS_ST + kk * 32 + quad * 8];
#pragma unroll
      for (int ct = 0; ct < 2; ++ct)
        bfv[ct] = *(const bf16x8*)&sm.lp.Bs[1][(wid * 32 + ct * 16 + l16) * BS_ST + kk * 32 + quad * 8];
#pragma unroll
      for (int rt = 0; rt < 2; ++rt)
#pragma unroll
        for (int ct = 0; ct < 2; ++ct)
          acc[rt][ct] = __builtin_amdgcn_mfma_f32_16x16x32_bf16(af[rt], bfv[ct], acc[rt][ct], 0, 0, 0);
    }
  }
  __syncthreads();  // all MFMA reads done before LDS reuse

  // ---- epilogue: Z (scaled by dinv[n]) -> LDS bf16 A-layout.
  // C/D layout of 16x16x32: col = lane&15, row = quad*4 + reg.
#pragma unroll
  for (int rt = 0; rt < 2; ++rt)
#pragma unroll
    for (int ct = 0; ct < 2; ++ct)
#pragma unroll
      for (int i = 0; i < 4; ++i) {
        int r = rt * 16 + quad * 4 + i;
        int c = wid * 32 + ct * 16 + l16;
        sm.Zs[r * ZS_ST + c] = __float2bfloat16(acc[rt][ct][i] * dinv_s[r]);
      }
  __syncthreads();

  // second GEMM: Z @ W via pre-transposed bf16 wt[o][f] (32 KB, L2-resident):
  // B-frag element j = W[f=kk*32+quad*8+j][o] = wt[o*128 + kk*32+quad*8+j].
  f32x4 acc2[2][2];
#pragma unroll
  for (int rt = 0; rt < 2; ++rt)
#pragma unroll
    for (int ct = 0; ct < 2; ++ct) acc2[rt][ct] = zero4;
#pragma unroll
  for (int kk = 0; kk < 4; ++kk) {
    bf16x8 za[2], wb[2];
#pragma unroll
    for (int rt = 0; rt < 2; ++rt)
      za[rt] = *(const bf16x8*)&sm.Zs[(rt * 16 + l16) * ZS_ST + kk * 32 + quad * 8];
#pragma unroll
    for (int ct = 0; ct < 2; ++ct) {
      const int o = wid * 32 + ct * 16 + l16;
      wb[ct] = *(const bf16x8*)&wt[(size_t)o * FDIM + kk * 32 + quad * 8];
    }
#pragma unroll
    for (int rt = 0; rt < 2; ++rt)
#pragma unroll
      for (int ct = 0; ct < 2; ++ct)
        acc2[rt][ct] = __builtin_amdgcn_mfma_f32_16x16x32_bf16(za[rt], wb[ct], acc2[rt][ct], 0, 0, 0);
  }

  float bv[2];
  bv[0] = bias[wid * 32 + l16];
  bv[1] = bias[wid * 32 + 16 + l16];
  float* ob = out + ((size_t)b * NROW + row0) * FDIM;
#pragma unroll
  for (int rt = 0; rt < 2; ++rt)
#pragma unroll
    for (int ct = 0; ct < 2; ++ct)
#pragma unroll
      for (int i = 0; i < 4; ++i) {
        int r = rt * 16 + quad * 4 + i;
        int o = wid * 32 + ct * 16 + l16;
        ob[(size_t)r * FDIM + o] = acc2[rt][ct][i] + bv[ct];
      }
}

extern "C" void kernel_launch(void* const* d_in, const int* in_sizes, int n_in,
                              void* d_out, int out_size, void* d_ws, size_t ws_size,
                              hipStream_t stream) {
  const float* x    = (const float*)d_in[0];   // [4,4096,128]
  const float* adj  = (const float*)d_in[1];   // [4,4096,4096]
  const float* w    = (const float*)d_in[2];   // [128,128]
  const float* bias = (const float*)d_in[3];   // [128]
  float* out = (float*)d_out;                  // [4,4096,128]

  float* dinv = (float*)d_ws;                                        // 64 KB
  __hip_bfloat16* xst =
      (__hip_bfloat16*)((char*)d_ws + (size_t)NBATCH * NROW * sizeof(float));  // 4 MiB
  __hip_bfloat16* wt =
      (__hip_bfloat16*)((char*)d_ws + (size_t)NBATCH * NROW * sizeof(float)
                        + (size_t)NBATCH * NROW * FDIM * sizeof(__hip_bfloat16)); // 32 KB

  k_degree<<<NBATCH * NROW / 4, 256, 0, stream>>>(adj, dinv);
  k_xst<<<513, 256, 0, stream>>>(x, dinv, xst, w, wt);
  k_gemm<<<512, 256, 0, stream>>>(adj, xst, dinv, wt, bias, out);
}